// Round 3
// baseline (793.333 us; speedup 1.0000x reference)
//
#include <hip/hip_runtime.h>
#include <hip/hip_bf16.h>

#define MDIM 4096      // B*S tokens
#define DDIM 512
#define HHEADS 8
#define SLEN 2048
#define TDIM 256
#define NBLK 256
#define NTHR 512
#define LDT 66
#define EXPC 0.1803368801111244f   // 0.125 * log2(e)

typedef __attribute__((ext_vector_type(8))) short short8;
typedef __attribute__((ext_vector_type(16))) float f32x16;

__device__ __forceinline__ unsigned short f2bf(float f) {
    union { __hip_bfloat16 h; unsigned short u; } c;
    c.h = __float2bfloat16(f);
    return c.u;
}
__device__ __forceinline__ float bf2f(short s) {
    return __uint_as_float((unsigned)(unsigned short)s << 16);
}

// LDS union across stages (max member 67.6 KB -> 1 block/CU, 2 waves/SIMD)
union Shm {
    struct { short As[128 * LDT]; short Bs[64 * LDT]; } g;       // gemm/qkv
    struct { short Ks[64 * 72]; short Vs[64 * 72]; } st[2];      // attn stage
    struct { float Om[256][64]; float Lm[2][256]; } mg;          // attn merge
};

struct KParams {
    const float *x, *Wq, *bq, *Wk, *bk, *Wv, *bv, *Wo, *bo, *g1, *be1;
    const float *W1, *b1, *W2, *b2, *g2, *be2, *Wp, *bp;
    float* out;
    short *xbf, *Qbuf, *Kbuf, *Vtbuf, *hcbf, *hidbf;
    float* y;
    short *Wqt, *Wkt, *Wvt, *Wot, *W1t, *W2t, *Wpt;
    unsigned* bar;
};

// Hand-rolled grid barrier: sense-reversal, device-scope atomics.
// SAFE: grid(256 blocks, 67.6KB LDS, <=256 VGPR) always fully co-resident
// (aggregate capacity >= 1 block/CU x 256 CUs), so no block waits unscheduled.
__device__ __forceinline__ void gridbar(unsigned* bar) {
    __syncthreads();
    if (threadIdx.x == 0) {
        __threadfence();
        unsigned gen = atomicAdd(&bar[1], 0u);
        unsigned arr = atomicAdd(&bar[0], 1u);
        if (arr == (unsigned)NBLK - 1u) {
            atomicExch(&bar[0], 0u);
            __threadfence();
            atomicAdd(&bar[1], 1u);
        } else {
            while (atomicAdd(&bar[1], 0u) == gen) __builtin_amdgcn_s_sleep(2);
        }
        __threadfence();
    }
    __syncthreads();
}

// ---------------------------------------------------------------------------
// 8-wave GEMM tile 128m x 64n, BK=64, waves (4m x 2n) of 32x32 MFMA.
// B transposed Bt[n][k]. flags: 1=relu, 2=bf16 out.
// ---------------------------------------------------------------------------
__device__ __forceinline__ void gemm_tile(Shm* shm,
    const short* __restrict__ A, const short* __restrict__ Bt,
    const float* __restrict__ bias, void* __restrict__ Cout,
    int N, int K, int flags, int m0, int n0)
{
    const int tid = threadIdx.x;
    const int wave = tid >> 6, lane = tid & 63;
    const int l31 = lane & 31, hi = lane >> 5;
    const int wm = wave >> 1, wn = wave & 1;

    f32x16 acc;
#pragma unroll
    for (int r = 0; r < 16; ++r) acc[r] = 0.f;

    const int ar = tid >> 2, ac = (tid & 3) * 16;   // A: 128 rows x 64
    const int br = tid >> 3, bc = (tid & 7) * 8;    // B: 64 rows x 64

    for (int k0 = 0; k0 < K; k0 += 64) {
        __syncthreads();
        *(short8*)&shm->g.As[ar * LDT + ac]     = *(const short8*)&A[(size_t)(m0 + ar) * K + k0 + ac];
        *(short8*)&shm->g.As[ar * LDT + ac + 8] = *(const short8*)&A[(size_t)(m0 + ar) * K + k0 + ac + 8];
        *(short8*)&shm->g.Bs[br * LDT + bc]     = *(const short8*)&Bt[(size_t)(n0 + br) * K + k0 + bc];
        __syncthreads();

        short8 af[4], bfm[4];
#pragma unroll
        for (int ks = 0; ks < 4; ++ks) {
            af[ks]  = *(const short8*)&shm->g.As[(wm * 32 + l31) * LDT + ks * 16 + hi * 8];
            bfm[ks] = *(const short8*)&shm->g.Bs[(wn * 32 + l31) * LDT + ks * 16 + hi * 8];
        }
#pragma unroll
        for (int ks = 0; ks < 4; ++ks)
            acc = __builtin_amdgcn_mfma_f32_32x32x16_bf16(af[ks], bfm[ks], acc, 0, 0, 0);
    }

    const int col = n0 + wn * 32 + l31;
    const float bb = bias[col];
    const int rbase = m0 + wm * 32 + 4 * hi;
#pragma unroll
    for (int r = 0; r < 16; ++r) {
        int row = rbase + (r & 3) + 8 * (r >> 2);
        float v = acc[r] + bb;
        if (flags & 1) v = fmaxf(v, 0.f);
        if (flags & 2) ((short*)Cout)[(size_t)row * N + col] = (short)f2bf(v);
        else           ((float*)Cout)[(size_t)row * N + col] = v;
    }
}

// ---------------------------------------------------------------------------
// 8-wave QKV tile 128m x 64a for one (which,h): Q pre-scaled; V transposed.
// ---------------------------------------------------------------------------
__device__ __forceinline__ void qkv_tile(Shm* shm, const KParams& P,
                                         int ncol, int m0, int layer)
{
    const int tid = threadIdx.x;
    const int wave = tid >> 6, lane = tid & 63;
    const int l31 = lane & 31, hi = lane >> 5;
    const int wm = wave >> 1, wn = wave & 1;
    const int which = ncol >> 3, h = ncol & 7;
    const size_t wOff = (size_t)layer * 262144;

    const short* Bt = ((which == 0) ? P.Wqt : (which == 1) ? P.Wkt : P.Wvt)
                      + wOff + (size_t)h * 64 * 512;
    const float* bias = ((which == 0) ? P.bq : (which == 1) ? P.bk : P.bv)
                        + layer * 512 + h * 64;
    short* Out = (which == 0) ? P.Qbuf : (which == 1) ? P.Kbuf : P.Vtbuf;

    f32x16 acc;
#pragma unroll
    for (int r = 0; r < 16; ++r) acc[r] = 0.f;

    const int ar = tid >> 2, ac = (tid & 3) * 16;
    const int br = tid >> 3, bc = (tid & 7) * 8;

    for (int k0 = 0; k0 < 512; k0 += 64) {
        __syncthreads();
        *(short8*)&shm->g.As[ar * LDT + ac]     = *(const short8*)&P.xbf[(size_t)(m0 + ar) * 512 + k0 + ac];
        *(short8*)&shm->g.As[ar * LDT + ac + 8] = *(const short8*)&P.xbf[(size_t)(m0 + ar) * 512 + k0 + ac + 8];
        *(short8*)&shm->g.Bs[br * LDT + bc]     = *(const short8*)&Bt[(size_t)br * 512 + k0 + bc];
        __syncthreads();

        short8 af[4], bfm[4];
#pragma unroll
        for (int ks = 0; ks < 4; ++ks) {
            af[ks]  = *(const short8*)&shm->g.As[(wm * 32 + l31) * LDT + ks * 16 + hi * 8];
            bfm[ks] = *(const short8*)&shm->g.Bs[(wn * 32 + l31) * LDT + ks * 16 + hi * 8];
        }
#pragma unroll
        for (int ks = 0; ks < 4; ++ks)
            acc = __builtin_amdgcn_mfma_f32_32x32x16_bf16(af[ks], bfm[ks], acc, 0, 0, 0);
    }

    const int a = wn * 32 + l31;
    const float bb = bias[a];
    const int b = m0 >> 11;
    const int sb = (m0 & (SLEN - 1)) + wm * 32;
    const int bh = b * HHEADS + h;

    if (which == 0) {
        short* Ob = Out + (size_t)bh * SLEN * 64;
#pragma unroll
        for (int r = 0; r < 16; ++r) {
            int s = sb + (r & 3) + 8 * (r >> 2) + 4 * hi;
            Ob[(size_t)s * 64 + a] = (short)f2bf((acc[r] + bb) * EXPC);
        }
    } else if (which == 1) {
        short* Ob = Out + (size_t)bh * SLEN * 64;
#pragma unroll
        for (int r = 0; r < 16; ++r) {
            int s = sb + (r & 3) + 8 * (r >> 2) + 4 * hi;
            Ob[(size_t)s * 64 + a] = (short)f2bf(acc[r] + bb);
        }
    } else {
        short* Ob = Out + ((size_t)bh * 64 + a) * SLEN;
#pragma unroll
        for (int g = 0; g < 4; ++g) {
            int s = sb + 8 * g + 4 * hi;
            ushort4 w;
            w.x = f2bf(acc[4 * g + 0] + bb);
            w.y = f2bf(acc[4 * g + 1] + bb);
            w.z = f2bf(acc[4 * g + 2] + bb);
            w.w = f2bf(acc[4 * g + 3] + bb);
            *(ushort4*)&Ob[s] = w;
        }
    }
}

// ---------------------------------------------------------------------------
// attn: 256 jobs = (qt 8 x sph 2 x bh 16), block = two 256-thr sub-blocks
// (sp = sph*2 + sub). Each sub: 256 q-rows (4 waves x 64q) x 512 keys,
// K/V LDS-staged (shared by 4 q-waves: traffic-optimal 64 MB/layer).
// fp32 in-LDS merge across subs, normalized bf16 straight to hc.
// ---------------------------------------------------------------------------
__device__ __forceinline__ void attn_stage(Shm* shm,
    const short* __restrict__ Qb, const short* __restrict__ Kb,
    const short* __restrict__ Vtb, short* __restrict__ hc)
{
    const int tid = threadIdx.x, bid = blockIdx.x;
    const int sub = tid >> 8;
    const int stid = tid & 255;
    const int wid = stid >> 6;
    const int lane = tid & 63, l31 = lane & 31, hi = lane >> 5;

    const int swz = (bid & 7) * 32 + (bid >> 3);   // XCD chunking: 2 bh per XCD
    const int qt = swz & 7, sph = (swz >> 3) & 1, bh = swz >> 4;
    const int sp = sph * 2 + sub;

    const short* Qg = Qb + (size_t)bh * SLEN * 64;
    const short* Kg = Kb + (size_t)bh * SLEN * 64;
    const short* Vg = Vtb + (size_t)bh * 64 * SLEN;
    const int q0 = qt * 256 + wid * 64;

    short8 qf[2][4];
#pragma unroll
    for (int nt = 0; nt < 2; ++nt)
#pragma unroll
        for (int ks = 0; ks < 4; ++ks)
            qf[nt][ks] = *(const short8*)&Qg[(size_t)(q0 + nt * 32 + l31) * 64 + ks * 16 + hi * 8];

    f32x16 oacc[2][2];
    float lsum[2] = {0.f, 0.f};
#pragma unroll
    for (int nt = 0; nt < 2; ++nt)
#pragma unroll
        for (int dt = 0; dt < 2; ++dt)
#pragma unroll
            for (int r = 0; r < 16; ++r) oacc[nt][dt][r] = 0.f;

    const int srow = stid >> 2;
    const int sch = (stid & 3) * 16;
    const int kbase = sp * 512;
    short* Ks = shm->st[sub].Ks;
    short* Vs = shm->st[sub].Vs;

#pragma unroll 1
    for (int kt = 0; kt < 8; ++kt) {
        const int k0 = kbase + kt * 64;
        __syncthreads();
        *(short8*)&Ks[srow * 72 + sch]     = *(const short8*)&Kg[(size_t)(k0 + srow) * 64 + sch];
        *(short8*)&Ks[srow * 72 + sch + 8] = *(const short8*)&Kg[(size_t)(k0 + srow) * 64 + sch + 8];
        *(short8*)&Vs[srow * 72 + sch]     = *(const short8*)&Vg[(size_t)srow * SLEN + k0 + sch];
        *(short8*)&Vs[srow * 72 + sch + 8] = *(const short8*)&Vg[(size_t)srow * SLEN + k0 + sch + 8];
        __syncthreads();

        short8 kf[2][4], vf[2][4];
#pragma unroll
        for (int mt = 0; mt < 2; ++mt)
#pragma unroll
            for (int ks = 0; ks < 4; ++ks)
                kf[mt][ks] = *(const short8*)&Ks[(mt * 32 + l31) * 72 + ks * 16 + hi * 8];
#pragma unroll
        for (int dt = 0; dt < 2; ++dt)
#pragma unroll
            for (int p = 0; p < 4; ++p)
                vf[dt][p] = *(const short8*)&Vs[(dt * 32 + l31) * 72 + p * 16 + hi * 8];

#pragma unroll
        for (int nt = 0; nt < 2; ++nt) {
            f32x16 sacc[2];
            __builtin_amdgcn_s_setprio(1);
#pragma unroll
            for (int mt = 0; mt < 2; ++mt) {
                f32x16 s;
#pragma unroll
                for (int r = 0; r < 16; ++r) s[r] = 0.f;
#pragma unroll
                for (int ks = 0; ks < 4; ++ks)
                    s = __builtin_amdgcn_mfma_f32_32x32x16_bf16(kf[mt][ks], qf[nt][ks], s, 0, 0, 0);
                sacc[mt] = s;
            }
            __builtin_amdgcn_s_setprio(0);

            int2 pk[2][4];
#pragma unroll
            for (int mt = 0; mt < 2; ++mt)
#pragma unroll
                for (int g = 0; g < 4; ++g) {
                    unsigned a0 = __float_as_uint(__builtin_amdgcn_exp2f(sacc[mt][4 * g + 0]));
                    unsigned a1 = __float_as_uint(__builtin_amdgcn_exp2f(sacc[mt][4 * g + 1]));
                    unsigned a2 = __float_as_uint(__builtin_amdgcn_exp2f(sacc[mt][4 * g + 2]));
                    unsigned a3 = __float_as_uint(__builtin_amdgcn_exp2f(sacc[mt][4 * g + 3]));
                    float t0 = __uint_as_float(a0 & 0xffff0000u);
                    float t1 = __uint_as_float(a1 & 0xffff0000u);
                    float t2 = __uint_as_float(a2 & 0xffff0000u);
                    float t3 = __uint_as_float(a3 & 0xffff0000u);
                    lsum[nt] += (t0 + t1) + (t2 + t3);
                    pk[mt][g].x = (int)__builtin_amdgcn_perm(a1, a0, 0x07060302u);
                    pk[mt][g].y = (int)__builtin_amdgcn_perm(a3, a2, 0x07060302u);
                }

            int2 xch[2][2];
#pragma unroll
            for (int mt = 0; mt < 2; ++mt)
#pragma unroll
                for (int h2 = 0; h2 < 2; ++h2) {
                    int2 v = hi ? pk[mt][2 * h2] : pk[mt][2 * h2 + 1];
                    xch[mt][h2].x = __shfl_xor(v.x, 32);
                    xch[mt][h2].y = __shfl_xor(v.y, 32);
                }

            __builtin_amdgcn_s_setprio(1);
#pragma unroll
            for (int p = 0; p < 4; ++p) {
                const int mt = p >> 1, h2 = p & 1;
                const int ga = 2 * h2, gb = 2 * h2 + 1;
                const int2 X = xch[mt][h2];
                union { int4 i; short8 s; } u;
                u.i.x = hi ? X.x : pk[mt][ga].x;
                u.i.y = hi ? X.y : pk[mt][ga].y;
                u.i.z = hi ? pk[mt][gb].x : X.x;
                u.i.w = hi ? pk[mt][gb].y : X.y;
#pragma unroll
                for (int dt = 0; dt < 2; ++dt)
                    oacc[nt][dt] = __builtin_amdgcn_mfma_f32_32x32x16_bf16(u.s, vf[dt][p], oacc[nt][dt], 0, 0, 0);
            }
            __builtin_amdgcn_s_setprio(0);
        }
    }

    // ---- in-block fp32 merge across the two sp sub-blocks ----
    float lt0 = lsum[0] + __shfl_xor(lsum[0], 32);
    float lt1 = lsum[1] + __shfl_xor(lsum[1], 32);
    __syncthreads();   // all stage-LDS reads done before union reuse
    if (hi == 0) {
        shm->mg.Lm[sub][wid * 64 + l31]      = lt0;
        shm->mg.Lm[sub][wid * 64 + 32 + l31] = lt1;
    }
    if (sub == 1) {
#pragma unroll
        for (int nt = 0; nt < 2; ++nt)
#pragma unroll
            for (int dt = 0; dt < 2; ++dt)
#pragma unroll
                for (int r = 0; r < 16; ++r) {
                    int qr = wid * 64 + nt * 32 + (r & 3) + 8 * (r >> 2) + 4 * hi;
                    shm->mg.Om[qr][dt * 32 + l31] = oacc[nt][dt][r];
                }
    }
    __syncthreads();
    if (sub == 0) {
        const int b = bh >> 3, h = bh & 7;
#pragma unroll
        for (int nt = 0; nt < 2; ++nt)
#pragma unroll
            for (int r = 0; r < 16; ++r) {
                int qr = wid * 64 + nt * 32 + (r & 3) + 8 * (r >> 2) + 4 * hi;
                float inv = 1.f / (shm->mg.Lm[0][qr] + shm->mg.Lm[1][qr]);
                size_t rowb = ((size_t)(b * SLEN + qt * 256 + qr)) * DDIM + h * 64;
#pragma unroll
                for (int dt = 0; dt < 2; ++dt)
                    hc[rowb + dt * 32 + l31] =
                        (short)f2bf((oacc[nt][dt][r] + shm->mg.Om[qr][dt * 32 + l31]) * inv);
            }
    }
}

// ---------------------------------------------------------------------------
// AddNorm: 16 rows per block (2 x 8 waves)
// ---------------------------------------------------------------------------
__device__ __forceinline__ void addnorm_rows(short* __restrict__ X,
    const float* __restrict__ Y, const float* __restrict__ g,
    const float* __restrict__ beta)
{
    const int lane = threadIdx.x & 63;
    const int c0 = lane * 8;
#pragma unroll
    for (int rr = 0; rr < 16; rr += 8) {
        const int t = blockIdx.x * 16 + rr + (threadIdx.x >> 6);
        short* xr = X + (size_t)t * DDIM;
        const float* yr = Y + (size_t)t * DDIM;

        short8 x8 = *(const short8*)&xr[c0];
        float4 y0 = *(const float4*)&yr[c0];
        float4 y1 = *(const float4*)&yr[c0 + 4];
        float v[8];
        v[0] = bf2f(x8[0]) + y0.x; v[1] = bf2f(x8[1]) + y0.y;
        v[2] = bf2f(x8[2]) + y0.z; v[3] = bf2f(x8[3]) + y0.w;
        v[4] = bf2f(x8[4]) + y1.x; v[5] = bf2f(x8[5]) + y1.y;
        v[6] = bf2f(x8[6]) + y1.z; v[7] = bf2f(x8[7]) + y1.w;

        float s1 = 0.f, s2 = 0.f;
#pragma unroll
        for (int j = 0; j < 8; ++j) { s1 += v[j]; s2 += v[j] * v[j]; }
#pragma unroll
        for (int off = 1; off < 64; off <<= 1) {
            s1 += __shfl_xor(s1, off);
            s2 += __shfl_xor(s2, off);
        }
        float mean = s1 * (1.0f / DDIM);
        float var = s2 * (1.0f / DDIM) - mean * mean;
        float rstd = rsqrtf(var + 1e-5f);

        float4 ga = *(const float4*)&g[c0];
        float4 gb = *(const float4*)&g[c0 + 4];
        float4 ba = *(const float4*)&beta[c0];
        float4 bb = *(const float4*)&beta[c0 + 4];
        float gg[8] = {ga.x, ga.y, ga.z, ga.w, gb.x, gb.y, gb.z, gb.w};
        float bt[8] = {ba.x, ba.y, ba.z, ba.w, bb.x, bb.y, bb.z, bb.w};

        short8 o8;
#pragma unroll
        for (int j = 0; j < 8; ++j)
            o8[j] = (short)f2bf((v[j] - mean) * rstd * gg[j] + bt[j]);
        *(short8*)&xr[c0] = o8;
    }
}

// ---------------------------------------------------------------------------
// The fused persistent kernel: prep -> 2x(qkv, attn, Wo, an1, ffn1, ffn2, an2)
// -> final proj, with hand-rolled grid barriers between stages.
// ---------------------------------------------------------------------------
#define N1 524288
#define N2 524288
#define NP 131072
#define PREP_TOT (3L * N1 + 3L * N2 + NP + 2097152L)

__global__ __launch_bounds__(NTHR, 2) void fused_k(KParams P)
{
    __shared__ Shm shm;
    const int tid = threadIdx.x;
    const int bid = blockIdx.x;

    // ---- prep (grid-stride) ----
    for (long idx0 = (long)bid * NTHR + tid; idx0 < PREP_TOT; idx0 += (long)NBLK * NTHR) {
        long idx = idx0;
        if (idx < 3L * N1) {
            int t = (int)(idx / N1);
            int r = (int)(idx % N1);
            int a = r & 63, k = (r >> 6) & 511, hh = r >> 15;
            const float* src = (t == 0) ? P.Wq : (t == 1) ? P.Wk : P.Wv;
            short* dst = (t == 0) ? P.Wqt : (t == 1) ? P.Wkt : P.Wvt;
            dst[((size_t)hh << 15) + (a << 9) + k] = (short)f2bf(src[r]);
            continue;
        }
        idx -= 3L * N1;
        if (idx < 3L * N2) {
            int t = (int)(idx / N2);
            int r = (int)(idx % N2);
            int n = r & 511, k = (r >> 9) & 511, i = r >> 18;
            const float* src = (t == 0) ? P.Wo : (t == 1) ? P.W1 : P.W2;
            short* dst = (t == 0) ? P.Wot : (t == 1) ? P.W1t : P.W2t;
            dst[((size_t)i << 18) + (n << 9) + k] = (short)f2bf(src[r]);
            continue;
        }
        idx -= 3L * N2;
        if (idx < NP) {
            int r = (int)idx;
            int n = r & 255, k = r >> 8;
            P.Wpt[n * 512 + k] = (short)f2bf(P.Wp[r]);
            continue;
        }
        idx -= NP;
        P.xbf[idx] = (short)f2bf(P.x[idx]);
    }
    gridbar(P.bar);

    for (int i = 0; i < 2; ++i) {
        const size_t wOff = (size_t)i * 262144;

        // qkv: 768 jobs (24 ncol x 32 mrow), 3 per block
#pragma unroll 1
        for (int j = 0; j < 3; ++j) {
            int job = bid + NBLK * j;
            qkv_tile(&shm, P, job % 24, (job / 24) * 128, i);
        }
        gridbar(P.bar);

        attn_stage(&shm, P.Qbuf, P.Kbuf, P.Vtbuf, P.hcbf);
        gridbar(P.bar);

        gemm_tile(&shm, P.hcbf, P.Wot + wOff, P.bo + i * 512, P.y,
                  512, 512, 0, (bid >> 3) * 128, (bid & 7) * 64);
        gridbar(P.bar);

        addnorm_rows(P.xbf, P.y, P.g1 + i * 512, P.be1 + i * 512);
        gridbar(P.bar);

        gemm_tile(&shm, P.xbf, P.W1t + wOff, P.b1 + i * 512, P.hidbf,
                  512, 512, 3, (bid >> 3) * 128, (bid & 7) * 64);
        gridbar(P.bar);

        gemm_tile(&shm, P.hidbf, P.W2t + wOff, P.b2 + i * 512, P.y,
                  512, 512, 0, (bid >> 3) * 128, (bid & 7) * 64);
        gridbar(P.bar);

        addnorm_rows(P.xbf, P.y, P.g2 + i * 512, P.be2 + i * 512);
        gridbar(P.bar);
    }

    // final projection: 128 jobs (32 m x 4 n)
    if (bid < 128)
        gemm_tile(&shm, P.xbf, P.Wpt, P.bp, P.out,
                  256, 512, 0, (bid >> 2) * 128, (bid & 3) * 64);
}

// ---------------------------------------------------------------------------
// Workspace (MiB), overlays lifetime-checked, < 40 MiB:
//   [ 0, 4) xbf   [ 4, 8) Qbuf   [ 8,12) Kbuf   [12,16) Vtbuf
//   [16,20) hcbf  [20,28) y fp32 [28,32) hidbf
//   [33,39.25) weights bf16      [39.5, +64B) grid barrier
// ---------------------------------------------------------------------------
extern "C" void kernel_launch(void* const* d_in, const int* in_sizes, int n_in,
                              void* d_out, int out_size, void* d_ws, size_t ws_size,
                              hipStream_t stream)
{
    (void)in_sizes; (void)n_in; (void)out_size; (void)ws_size;
    char* wsb = (char*)d_ws;
    const size_t MB = 1024 * 1024;

    KParams P;
    P.x   = (const float*)d_in[0];
    P.Wq  = (const float*)d_in[1];
    P.bq  = (const float*)d_in[2];
    P.Wk  = (const float*)d_in[3];
    P.bk  = (const float*)d_in[4];
    P.Wv  = (const float*)d_in[5];
    P.bv  = (const float*)d_in[6];
    P.Wo  = (const float*)d_in[7];
    P.bo  = (const float*)d_in[8];
    P.g1  = (const float*)d_in[9];
    P.be1 = (const float*)d_in[10];
    P.W1  = (const float*)d_in[11];
    P.b1  = (const float*)d_in[12];
    P.W2  = (const float*)d_in[13];
    P.b2  = (const float*)d_in[14];
    P.g2  = (const float*)d_in[15];
    P.be2 = (const float*)d_in[16];
    P.Wp  = (const float*)d_in[17];
    P.bp  = (const float*)d_in[18];
    P.out = (float*)d_out;

    P.xbf   = (short*)(wsb + 0);
    P.Qbuf  = (short*)(wsb + 4 * MB);
    P.Kbuf  = (short*)(wsb + 8 * MB);
    P.Vtbuf = (short*)(wsb + 12 * MB);
    P.hcbf  = (short*)(wsb + 16 * MB);
    P.y     = (float*)(wsb + 20 * MB);
    P.hidbf = (short*)(wsb + 28 * MB);
    P.Wqt   = (short*)(wsb + 33 * MB);
    P.Wkt   = (short*)(wsb + 34 * MB);
    P.Wvt   = (short*)(wsb + 35 * MB);
    P.Wot   = (short*)(wsb + 36 * MB);
    P.W1t   = (short*)(wsb + 37 * MB);
    P.W2t   = (short*)(wsb + 38 * MB);
    P.Wpt   = (short*)(wsb + 39 * MB);
    P.bar   = (unsigned*)(wsb + 39 * MB + 512 * 1024);

    hipMemsetAsync(P.bar, 0, 64, stream);
    fused_k<<<NBLK, NTHR, 0, stream>>>(P);
}